// Round 5
// baseline (1303.512 us; speedup 1.0000x reference)
//
#include <hip/hip_runtime.h>
#include <stdint.h>

typedef unsigned short u16;
typedef unsigned int   u32;

#define NN 50000
#define NE 400000

typedef __bf16 bf16x8 __attribute__((ext_vector_type(8)));
typedef u16    u16x8  __attribute__((ext_vector_type(8)));
typedef float  f32x4  __attribute__((ext_vector_type(4)));

__device__ __forceinline__ float bf2f(u16 b) {
  union { u32 u; float f; } v; v.u = ((u32)b) << 16; return v.f;
}
__device__ __forceinline__ u16 f2bf(float f) {
  union { float f; u32 u; } v; v.f = f;
  u32 r = v.u + 0x7fffu + ((v.u >> 16) & 1u);
  return (u16)(r >> 16);
}

// ---------------- setup kernels ----------------

__global__ void zero_int_kernel(int* __restrict__ p, int n) {
  int i = blockIdx.x * blockDim.x + threadIdx.x;
  if (i < n) p[i] = 0;
}

__global__ void count_deg_kernel(const int* __restrict__ dst, int* __restrict__ deg, int e) {
  int i = blockIdx.x * blockDim.x + threadIdx.x;
  if (i < e) atomicAdd(&deg[dst[i]], 1);
}

__global__ void dinv_kernel(const int* __restrict__ deg, float* __restrict__ dinv, int n) {
  int i = blockIdx.x * blockDim.x + threadIdx.x;
  if (i < n) dinv[i] = rsqrtf((float)deg[i] + 1.0f);
}

__global__ __launch_bounds__(1024) void scan_kernel(const int* __restrict__ counts,
                                                    int* __restrict__ offsets, int n) {
  __shared__ int wsums[17];
  __shared__ int carry;
  int tid = threadIdx.x;
  int lane = tid & 63, wid = tid >> 6;
  if (tid == 0) carry = 0;
  __syncthreads();
  for (int base = 0; base < n; base += 1024) {
    int i = base + tid;
    int v = (i < n) ? counts[i] : 0;
    int s = v;
    #pragma unroll
    for (int off = 1; off < 64; off <<= 1) {
      int t = __shfl_up(s, off, 64);
      if (lane >= off) s += t;
    }
    if (lane == 63) wsums[wid] = s;
    __syncthreads();
    if (tid == 0) {
      int a = 0;
      #pragma unroll
      for (int w = 0; w < 16; ++w) { int t = wsums[w]; wsums[w] = a; a += t; }
      wsums[16] = a;
    }
    __syncthreads();
    if (i < n) offsets[i] = carry + wsums[wid] + s - v;
    __syncthreads();
    if (tid == 0) carry += wsums[16];
    __syncthreads();
  }
  if (tid == 0) offsets[n] = carry;
}

__global__ void csr_fill_kernel(const int* __restrict__ src, const int* __restrict__ dst,
                                const int* __restrict__ offsets, int* __restrict__ cursor,
                                const float* __restrict__ dinv,
                                int2* __restrict__ csr_pack, int e) {
  int i = blockIdx.x * blockDim.x + threadIdx.x;
  if (i < e) {
    int s = src[i], d = dst[i];
    int pos = offsets[d] + atomicAdd(&cursor[d], 1);
    float nr = dinv[s] * dinv[d];
    csr_pack[pos] = make_int2(s, __float_as_int(nr));
  }
}

__global__ void f2bf_kernel(const float* __restrict__ in, u16* __restrict__ out, int n) {
  int i = blockIdx.x * blockDim.x + threadIdx.x;
  if (i < n) out[i] = f2bf(in[i]);
}

// W (K x N, row-major fp32) -> Wt (N x K, row-major bf16)
__global__ void wt_kernel(const float* __restrict__ W, u16* __restrict__ Wt, int K, int N) {
  int i = blockIdx.x * blockDim.x + threadIdx.x;
  if (i < K * N) {
    int k = i / N;
    int n2 = i - k * N;
    Wt[n2 * K + k] = f2bf(W[i]);
  }
}

// ---------------- aggregation: XCD feature-chunked ----------------
// chunk = bid & 7 (mapping empirically validated by R3 GEMM FETCH drop).
// Each XCD gathers only its F/8-feature slab -> slab working set ~footprint/8
// stays hot in that XCD's L2/L3 instead of thrashing all 8 L2s with the full
// matrix. Edge meta loaded nontemporally (streamed 8x, don't pollute slab).

template<int G, bool HAS_BIAS, bool RELU, bool OUT_BF, bool OUT_F32>
__global__ __launch_bounds__(256) void agg8c_kernel(
    const u16* __restrict__ g, const int* __restrict__ rowptr,
    const int2* __restrict__ csr_pack,
    const float* __restrict__ dinv, const float* __restrict__ bias,
    u16* __restrict__ outb, float* __restrict__ outf)
{
  constexpr int F = G * 8;
  constexpr int GC = G / 8;          // groups per chunk
  int chunk = blockIdx.x & 7;
  int cidx = (blockIdx.x >> 3) * 256 + threadIdx.x;
  if (cidx >= NN * GC) return;
  int v = cidx / GC;
  int gl = cidx - v * GC;
  int g8 = chunk * GC + gl;
  const u16* base = g + g8 * 8;

  float acc[8];
  #pragma unroll
  for (int k = 0; k < 8; ++k) acc[k] = 0.f;

  int e0 = rowptr[v], e1 = rowptr[v + 1];
  int e = e0;
  for (; e + 3 < e1; e += 4) {
    long long q0 = __builtin_nontemporal_load((const long long*)&csr_pack[e]);
    long long q1 = __builtin_nontemporal_load((const long long*)&csr_pack[e + 1]);
    long long q2 = __builtin_nontemporal_load((const long long*)&csr_pack[e + 2]);
    long long q3 = __builtin_nontemporal_load((const long long*)&csr_pack[e + 3]);
    u16x8 r0 = *(const u16x8*)(base + (size_t)(int)q0 * F);
    u16x8 r1 = *(const u16x8*)(base + (size_t)(int)q1 * F);
    u16x8 r2 = *(const u16x8*)(base + (size_t)(int)q2 * F);
    u16x8 r3 = *(const u16x8*)(base + (size_t)(int)q3 * F);
    float n0 = __int_as_float((int)(q0 >> 32)), n1 = __int_as_float((int)(q1 >> 32));
    float n2 = __int_as_float((int)(q2 >> 32)), n3 = __int_as_float((int)(q3 >> 32));
    #pragma unroll
    for (int k = 0; k < 8; ++k) acc[k] += n0 * bf2f(r0[k]);
    #pragma unroll
    for (int k = 0; k < 8; ++k) acc[k] += n1 * bf2f(r1[k]);
    #pragma unroll
    for (int k = 0; k < 8; ++k) acc[k] += n2 * bf2f(r2[k]);
    #pragma unroll
    for (int k = 0; k < 8; ++k) acc[k] += n3 * bf2f(r3[k]);
  }
  for (; e < e1; ++e) {
    long long q0 = __builtin_nontemporal_load((const long long*)&csr_pack[e]);
    u16x8 r0 = *(const u16x8*)(base + (size_t)(int)q0 * F);
    float n0 = __int_as_float((int)(q0 >> 32));
    #pragma unroll
    for (int k = 0; k < 8; ++k) acc[k] += n0 * bf2f(r0[k]);
  }

  float sv = dinv[v]; sv *= sv;
  u16x8 sr = *(const u16x8*)(base + (size_t)v * F);
  float vals[8];
  #pragma unroll
  for (int k = 0; k < 8; ++k) {
    float val = acc[k] + sv * bf2f(sr[k]);
    if (HAS_BIAS) val += bias[g8 * 8 + k];
    if (RELU) val = fmaxf(val, 0.f);
    vals[k] = val;
  }
  if (OUT_BF) {
    u16x8 ob;
    #pragma unroll
    for (int k = 0; k < 8; ++k) ob[k] = f2bf(vals[k]);
    *(u16x8*)(outb + (size_t)v * F + g8 * 8) = ob;
  }
  if (OUT_F32) {
    f32x4 o0, o1;
    #pragma unroll
    for (int k = 0; k < 4; ++k) { o0[k] = vals[k]; o1[k] = vals[4 + k]; }
    float* op = outf + (size_t)v * F + g8 * 8;
    *(f32x4*)op = o0;
    *(f32x4*)(op + 4) = o1;
  }
}

static inline int aggc_grid(int G) {
  int GC = G / 8;
  return ((NN * GC + 255) / 256) * 8;
}

__global__ void agg_small_kernel(const u16* __restrict__ g, const int* __restrict__ rowptr,
                                 const int2* __restrict__ csr_pack,
                                 const float* __restrict__ dinv, const float* __restrict__ bias,
                                 float* __restrict__ out, int n, int F) {
  int idx = blockIdx.x * blockDim.x + threadIdx.x;
  if (idx >= n * F) return;
  int v = idx / F;
  int f = idx - v * F;
  float acc = 0.f;
  int e1 = rowptr[v + 1];
  for (int e = rowptr[v]; e < e1; ++e) {
    int2 p = csr_pack[e];
    acc += __int_as_float(p.y) * bf2f(g[p.x * F + f]);
  }
  float dv = dinv[v];
  out[idx] = acc + dv * dv * bf2f(g[v * F + f]) + bias[f];
}

// ---------------- GEMM (A: MxK bf16 row-major, Bt: NxK bf16 row-major) ----------------
// XCD supertile (verified: FETCH 465->96MB) + quad swizzle (verified: conflicts 0)
// + dbuf K-loop. NEW: __launch_bounds__(256,4) caps unified VGPR+AGPR at 128
// -> 4 blocks/CU instead of 3 (was 132 regs -> 3 waves/SIMD, occupancy 30%).

#define BM 128
#define BN 128
#define BK 32

// gfx9 s_waitcnt simm16: vmcnt[3:0]|expcnt[6:4]|lgkmcnt[11:8]|vmcnt_hi[15:14]
#define WAIT_VMCNT4 0x0F74   // vmcnt(4), lgkm/exp = no-wait
#define WAIT_VMCNT0 0x0F70   // vmcnt(0), lgkm/exp = no-wait

__device__ __forceinline__ void gl_lds16(const void* g, void* l) {
  __builtin_amdgcn_global_load_lds((const __attribute__((address_space(1))) void*)g,
                                   (__attribute__((address_space(3))) void*)l, 16, 0, 0);
}

template<bool BIAS_RELU>
__global__ __launch_bounds__(256, 4) void gemm_bt_kernel(
    const u16* __restrict__ A, const u16* __restrict__ Bt,
    u16* __restrict__ C, const float* __restrict__ bias,
    int M, int N, int K)
{
  __shared__ __align__(16) u16 As[2][BM * BK];
  __shared__ __align__(16) u16 Bs[2][BN * BK];
  int gm = (M + BM - 1) / BM;
  int gn = (N + BN - 1) / BN;
  int bid = blockIdx.x;
  int xcd = bid & 7;
  int t = bid >> 3;
  int trow = t / gn;
  int bn_i = t - trow * gn;
  int row = trow * 8 + xcd;
  if (row >= gm) return;
  int bm = row * BM, bn = bn_i * BN;

  int tid = threadIdx.x;
  int wave = tid >> 6, lane = tid & 63;
  int wm = wave & 1, wn = wave >> 1;

  // staging: 4 lanes per 32-elem row; logical quad permuted -> swizzled LDS layout
  int srow = tid >> 2;                                // 0..63
  int sq_log = ((tid & 3) - ((tid >> 3) & 3)) & 3;    // logical quad this lane stages
  int ar0 = min(bm + srow, M - 1);
  int ar1 = min(bm + 64 + srow, M - 1);
  int br0 = min(bn + srow, N - 1);
  int br1 = min(bn + 64 + srow, N - 1);
  const u16* ag0 = A + (size_t)ar0 * K + sq_log * 8;
  const u16* ag1 = A + (size_t)ar1 * K + sq_log * 8;
  const u16* bg0 = Bt + (size_t)br0 * K + sq_log * 8;
  const u16* bg1 = Bt + (size_t)br1 * K + sq_log * 8;
  int la0 = (wave * 16) * BK;
  int la1 = (64 + wave * 16) * BK;

  f32x4 acc[4][4];
  #pragma unroll
  for (int i = 0; i < 4; ++i)
    #pragma unroll
    for (int j = 0; j < 4; ++j)
      acc[i][j] = (f32x4){0.f, 0.f, 0.f, 0.f};

  int row16 = lane & 15, q = lane >> 4;
  int perm = (q + (row16 >> 1)) & 3;                  // physical quad for logical quad q
  int ard = (wm * 64 + row16) * BK + perm * 8;
  int brd = (wn * 64 + row16) * BK + perm * 8;

  const int iters = K / BK;

  // prologue: stage tile 0 into buffer 0
  gl_lds16(ag0, &As[0][la0]);
  gl_lds16(ag1, &As[0][la1]);
  gl_lds16(bg0, &Bs[0][la0]);
  gl_lds16(bg1, &Bs[0][la1]);

  int buf = 0;
  for (int it = 0; it < iters; ++it) {
    __builtin_amdgcn_s_barrier();
    if (it + 1 < iters) {
      int kn = (it + 1) * BK;
      gl_lds16(ag0 + kn, &As[buf ^ 1][la0]);
      gl_lds16(ag1 + kn, &As[buf ^ 1][la1]);
      gl_lds16(bg0 + kn, &Bs[buf ^ 1][la0]);
      gl_lds16(bg1 + kn, &Bs[buf ^ 1][la1]);
      __builtin_amdgcn_s_waitcnt(WAIT_VMCNT4);  // wait only current buf's 4 loads
    } else {
      __builtin_amdgcn_s_waitcnt(WAIT_VMCNT0);
    }
    __builtin_amdgcn_s_barrier();

    bf16x8 af[4], bfr[4];
    #pragma unroll
    for (int i = 0; i < 4; ++i) af[i] = *(const bf16x8*)(&As[buf][ard + i * 16 * BK]);
    #pragma unroll
    for (int j = 0; j < 4; ++j) bfr[j] = *(const bf16x8*)(&Bs[buf][brd + j * 16 * BK]);
    #pragma unroll
    for (int i = 0; i < 4; ++i)
      #pragma unroll
      for (int j = 0; j < 4; ++j)
        acc[i][j] = __builtin_amdgcn_mfma_f32_16x16x32_bf16(af[i], bfr[j], acc[i][j], 0, 0, 0);
    buf ^= 1;
  }

  // epilogue: C/D layout col=lane&15, row=(lane>>4)*4+reg  [verified m89/m91]
  #pragma unroll
  for (int i = 0; i < 4; ++i) {
    int rbase = bm + wm * 64 + i * 16 + q * 4;
    #pragma unroll
    for (int j = 0; j < 4; ++j) {
      int col = bn + wn * 64 + j * 16 + row16;
      if (col < N) {
        float bv = BIAS_RELU ? bias[col] : 0.f;
        #pragma unroll
        for (int r = 0; r < 4; ++r) {
          int gr = rbase + r;
          if (gr < M) {
            float val = acc[i][j][r];
            if (BIAS_RELU) { val += bv; val = fmaxf(val, 0.f); }
            C[(size_t)gr * N + col] = f2bf(val);
          }
        }
      }
    }
  }
}

static inline int gemm_grid(int M, int N) {
  int gm = (M + BM - 1) / BM;
  int gn = (N + BN - 1) / BN;
  int rows_per_xcd = (gm + 7) / 8;
  return rows_per_xcd * gn * 8;
}

// ---------------- launch ----------------

extern "C" void kernel_launch(void* const* d_in, const int* in_sizes, int n_in,
                              void* d_out, int out_size, void* d_ws, size_t ws_size,
                              hipStream_t stream) {
  const float* x   = (const float*)d_in[0];
  const int* ei    = (const int*)d_in[1];
  const int* src   = ei;
  const int* dst   = ei + NE;
  const float* W1  = (const float*)d_in[2];
  const float* b1  = (const float*)d_in[3];
  const float* W2  = (const float*)d_in[4];
  const float* b2  = (const float*)d_in[5];
  const float* W3  = (const float*)d_in[6];
  const float* b3  = (const float*)d_in[7];
  const float* W4  = (const float*)d_in[8];
  const float* b4  = (const float*)d_in[9];
  const float* W5  = (const float*)d_in[10];
  const float* b5  = (const float*)d_in[11];
  float* out_h = (float*)d_out;                       // 50000 x 192
  float* out_o = (float*)d_out + (size_t)NN * 192;    // 50000 x 5

  char* p = (char*)d_ws;
  auto alloc = [&](size_t bytes) { char* r = p; p += (bytes + 255) & ~(size_t)255; return r; };
  int*   deg      = (int*)alloc((size_t)NN * 4);
  int*   cursor   = (int*)alloc((size_t)NN * 4);
  float* dinv     = (float*)alloc((size_t)NN * 4);
  int*   offs     = (int*)alloc((size_t)(NN + 1) * 4);
  int2*  csr_pack = (int2*)alloc((size_t)NE * 8);
  u16* W1t = (u16*)alloc((size_t)768 * 1536 * 2);
  u16* W2t = (u16*)alloc((size_t)1536 * 768 * 2);
  u16* W3t = (u16*)alloc((size_t)768 * 384 * 2);
  u16* W4t = (u16*)alloc((size_t)384 * 192 * 2);
  u16* W5t = (u16*)alloc((size_t)192 * 5 * 2);
  u16* B0 = (u16*)alloc((size_t)NN * 768 * 2);
  u16* B1 = (u16*)alloc((size_t)NN * 768 * 2);
  u16* B2 = (u16*)alloc((size_t)NN * 1536 * 2);

  u16* xb  = B0;
  u16* a0  = B1;
  u16* h1  = B2;
  u16* g2  = B0;
  u16* h2  = B1;
  u16* g3  = B0;
  u16* h3  = B2;
  u16* g4  = B0;
  u16* h4b = B1;
  u16* g5  = B0;

  const int M = NN;

  // degree / CSR build
  zero_int_kernel<<<(NN + 255) / 256, 256, 0, stream>>>(deg, NN);
  zero_int_kernel<<<(NN + 255) / 256, 256, 0, stream>>>(cursor, NN);
  count_deg_kernel<<<(NE + 255) / 256, 256, 0, stream>>>(dst, deg, NE);
  dinv_kernel<<<(NN + 255) / 256, 256, 0, stream>>>(deg, dinv, NN);
  scan_kernel<<<1, 1024, 0, stream>>>(deg, offs, NN);
  csr_fill_kernel<<<(NE + 255) / 256, 256, 0, stream>>>(src, dst, offs, cursor, dinv,
                                                        csr_pack, NE);
  // dtype conversions
  f2bf_kernel<<<((NN * 768) + 255) / 256, 256, 0, stream>>>(x, xb, NN * 768);
  wt_kernel<<<((768 * 1536) + 255) / 256, 256, 0, stream>>>(W1, W1t, 768, 1536);
  wt_kernel<<<((1536 * 768) + 255) / 256, 256, 0, stream>>>(W2, W2t, 1536, 768);
  wt_kernel<<<((768 * 384) + 255) / 256, 256, 0, stream>>>(W3, W3t, 768, 384);
  wt_kernel<<<((384 * 192) + 255) / 256, 256, 0, stream>>>(W4, W4t, 384, 192);
  wt_kernel<<<((192 * 5) + 255) / 256, 256, 0, stream>>>(W5, W5t, 192, 5);

  dim3 blk(256);

  // layer 1: aggregate-first  (Ahat x) W1 + b1, relu
  agg8c_kernel<96, false, false, true, false><<<aggc_grid(96), blk, 0, stream>>>(
      xb, offs, csr_pack, dinv, nullptr, a0, nullptr);
  gemm_bt_kernel<true><<<gemm_grid(M, 1536), blk, 0, stream>>>(
      a0, W1t, h1, b1, M, 1536, 768);

  // layer 2
  gemm_bt_kernel<false><<<gemm_grid(M, 768), blk, 0, stream>>>(
      h1, W2t, g2, nullptr, M, 768, 1536);
  agg8c_kernel<96, true, true, true, false><<<aggc_grid(96), blk, 0, stream>>>(
      g2, offs, csr_pack, dinv, b2, h2, nullptr);

  // layer 3
  gemm_bt_kernel<false><<<gemm_grid(M, 384), blk, 0, stream>>>(
      h2, W3t, g3, nullptr, M, 384, 768);
  agg8c_kernel<48, true, true, true, false><<<aggc_grid(48), blk, 0, stream>>>(
      g3, offs, csr_pack, dinv, b3, h3, nullptr);

  // layer 4 (output 0: fp32 h to d_out, bf16 copy for layer 5)
  gemm_bt_kernel<false><<<gemm_grid(M, 192), blk, 0, stream>>>(
      h3, W4t, g4, nullptr, M, 192, 384);
  agg8c_kernel<24, true, true, true, true><<<aggc_grid(24), blk, 0, stream>>>(
      g4, offs, csr_pack, dinv, b4, h4b, out_h);

  // layer 5 (output 1)
  gemm_bt_kernel<false><<<gemm_grid(M, 5), blk, 0, stream>>>(
      h4b, W5t, g5, nullptr, M, 5, 192);
  agg_small_kernel<<<((NN * 5) + 255) / 256, 256, 0, stream>>>(
      g5, offs, csr_pack, dinv, b5, out_o, NN, 5);
}

// Round 6
// 1091.130 us; speedup vs baseline: 1.1946x; 1.1946x over previous
//
#include <hip/hip_runtime.h>
#include <stdint.h>

typedef unsigned short u16;
typedef unsigned int   u32;

#define NN 50000
#define NE 400000

typedef __bf16 bf16x8 __attribute__((ext_vector_type(8)));
typedef u16    u16x8  __attribute__((ext_vector_type(8)));
typedef float  f32x4  __attribute__((ext_vector_type(4)));

__device__ __forceinline__ float bf2f(u16 b) {
  union { u32 u; float f; } v; v.u = ((u32)b) << 16; return v.f;
}
__device__ __forceinline__ u16 f2bf(float f) {
  union { float f; u32 u; } v; v.f = f;
  u32 r = v.u + 0x7fffu + ((v.u >> 16) & 1u);
  return (u16)(r >> 16);
}

// ---------------- setup kernels ----------------

__global__ void zero_int_kernel(int* __restrict__ p, int n) {
  int i = blockIdx.x * blockDim.x + threadIdx.x;
  if (i < n) p[i] = 0;
}

__global__ void count_deg_kernel(const int* __restrict__ dst, int* __restrict__ deg, int e) {
  int i = blockIdx.x * blockDim.x + threadIdx.x;
  if (i < e) atomicAdd(&deg[dst[i]], 1);
}

__global__ void dinv_kernel(const int* __restrict__ deg, float* __restrict__ dinv, int n) {
  int i = blockIdx.x * blockDim.x + threadIdx.x;
  if (i < n) dinv[i] = rsqrtf((float)deg[i] + 1.0f);
}

__global__ __launch_bounds__(1024) void scan_kernel(const int* __restrict__ counts,
                                                    int* __restrict__ offsets, int n) {
  __shared__ int wsums[17];
  __shared__ int carry;
  int tid = threadIdx.x;
  int lane = tid & 63, wid = tid >> 6;
  if (tid == 0) carry = 0;
  __syncthreads();
  for (int base = 0; base < n; base += 1024) {
    int i = base + tid;
    int v = (i < n) ? counts[i] : 0;
    int s = v;
    #pragma unroll
    for (int off = 1; off < 64; off <<= 1) {
      int t = __shfl_up(s, off, 64);
      if (lane >= off) s += t;
    }
    if (lane == 63) wsums[wid] = s;
    __syncthreads();
    if (tid == 0) {
      int a = 0;
      #pragma unroll
      for (int w = 0; w < 16; ++w) { int t = wsums[w]; wsums[w] = a; a += t; }
      wsums[16] = a;
    }
    __syncthreads();
    if (i < n) offsets[i] = carry + wsums[wid] + s - v;
    __syncthreads();
    if (tid == 0) carry += wsums[16];
    __syncthreads();
  }
  if (tid == 0) offsets[n] = carry;
}

__global__ void csr_fill_kernel(const int* __restrict__ src, const int* __restrict__ dst,
                                const int* __restrict__ offsets, int* __restrict__ cursor,
                                const float* __restrict__ dinv,
                                int2* __restrict__ csr_pack, int e) {
  int i = blockIdx.x * blockDim.x + threadIdx.x;
  if (i < e) {
    int s = src[i], d = dst[i];
    int pos = offsets[d] + atomicAdd(&cursor[d], 1);
    float nr = dinv[s] * dinv[d];
    csr_pack[pos] = make_int2(s, __float_as_int(nr));
  }
}

__global__ void f2bf_kernel(const float* __restrict__ in, u16* __restrict__ out, int n) {
  int i = blockIdx.x * blockDim.x + threadIdx.x;
  if (i < n) out[i] = f2bf(in[i]);
}

// W (K x N, row-major fp32) -> Wt (N x K, row-major bf16)
__global__ void wt_kernel(const float* __restrict__ W, u16* __restrict__ Wt, int K, int N) {
  int i = blockIdx.x * blockDim.x + threadIdx.x;
  if (i < K * N) {
    int k = i / N;
    int n2 = i - k * N;
    Wt[n2 * K + k] = f2bf(W[i]);
  }
}

// ---------------- aggregation: one thread per (node, 8-feature group) ----------------
// R4-verified version. NOTE (R5 lesson): do NOT XCD-chunk features here — with
// fewer threads/node a wave spans ~6 nodes and runs at wave-max degree, and the
// feature matrix is already L3-resident; chunking cost ~200us.

template<int G, bool HAS_BIAS, bool RELU, bool OUT_BF, bool OUT_F32>
__global__ __launch_bounds__(256) void agg8_kernel(
    const u16* __restrict__ g, const int* __restrict__ rowptr,
    const int2* __restrict__ csr_pack,
    const float* __restrict__ dinv, const float* __restrict__ bias,
    u16* __restrict__ outb, float* __restrict__ outf)
{
  constexpr int F = G * 8;
  int idx = blockIdx.x * blockDim.x + threadIdx.x;
  if (idx >= NN * G) return;
  int v = idx / G;
  int g8 = idx - v * G;
  const u16* base = g + g8 * 8;

  float acc[8];
  #pragma unroll
  for (int k = 0; k < 8; ++k) acc[k] = 0.f;

  int e0 = rowptr[v], e1 = rowptr[v + 1];
  int e = e0;
  for (; e + 3 < e1; e += 4) {
    int2 p0 = csr_pack[e];
    int2 p1 = csr_pack[e + 1];
    int2 p2 = csr_pack[e + 2];
    int2 p3 = csr_pack[e + 3];
    u16x8 r0 = *(const u16x8*)(base + (size_t)p0.x * F);
    u16x8 r1 = *(const u16x8*)(base + (size_t)p1.x * F);
    u16x8 r2 = *(const u16x8*)(base + (size_t)p2.x * F);
    u16x8 r3 = *(const u16x8*)(base + (size_t)p3.x * F);
    float n0 = __int_as_float(p0.y), n1 = __int_as_float(p1.y);
    float n2 = __int_as_float(p2.y), n3 = __int_as_float(p3.y);
    #pragma unroll
    for (int k = 0; k < 8; ++k) acc[k] += n0 * bf2f(r0[k]);
    #pragma unroll
    for (int k = 0; k < 8; ++k) acc[k] += n1 * bf2f(r1[k]);
    #pragma unroll
    for (int k = 0; k < 8; ++k) acc[k] += n2 * bf2f(r2[k]);
    #pragma unroll
    for (int k = 0; k < 8; ++k) acc[k] += n3 * bf2f(r3[k]);
  }
  for (; e < e1; ++e) {
    int2 p0 = csr_pack[e];
    u16x8 r0 = *(const u16x8*)(base + (size_t)p0.x * F);
    float n0 = __int_as_float(p0.y);
    #pragma unroll
    for (int k = 0; k < 8; ++k) acc[k] += n0 * bf2f(r0[k]);
  }

  float sv = dinv[v]; sv *= sv;
  u16x8 sr = *(const u16x8*)(base + (size_t)v * F);
  float vals[8];
  #pragma unroll
  for (int k = 0; k < 8; ++k) {
    float val = acc[k] + sv * bf2f(sr[k]);
    if (HAS_BIAS) val += bias[g8 * 8 + k];
    if (RELU) val = fmaxf(val, 0.f);
    vals[k] = val;
  }
  if (OUT_BF) {
    u16x8 ob;
    #pragma unroll
    for (int k = 0; k < 8; ++k) ob[k] = f2bf(vals[k]);
    *(u16x8*)(outb + (size_t)v * F + g8 * 8) = ob;
  }
  if (OUT_F32) {
    f32x4 o0, o1;
    #pragma unroll
    for (int k = 0; k < 4; ++k) { o0[k] = vals[k]; o1[k] = vals[4 + k]; }
    float* op = outf + (size_t)v * F + g8 * 8;
    *(f32x4*)op = o0;
    *(f32x4*)(op + 4) = o1;
  }
}

__global__ void agg_small_kernel(const u16* __restrict__ g, const int* __restrict__ rowptr,
                                 const int2* __restrict__ csr_pack,
                                 const float* __restrict__ dinv, const float* __restrict__ bias,
                                 float* __restrict__ out, int n, int F) {
  int idx = blockIdx.x * blockDim.x + threadIdx.x;
  if (idx >= n * F) return;
  int v = idx / F;
  int f = idx - v * F;
  float acc = 0.f;
  int e1 = rowptr[v + 1];
  for (int e = rowptr[v]; e < e1; ++e) {
    int2 p = csr_pack[e];
    acc += __int_as_float(p.y) * bf2f(g[p.x * F + f]);
  }
  float dv = dinv[v];
  out[idx] = acc + dv * dv * bf2f(g[v * F + f]) + bias[f];
}

// ---------------- GEMM (A: MxK bf16 row-major, Bt: NxK bf16 row-major) ----------------
// XCD supertile (verified R3: FETCH 465->96MB) + quad swizzle (verified R3:
// conflicts 0) + dbuf K-loop + __launch_bounds__(256,4) (verified R5:
// VGPR 56, occupancy 30->42.7%, 230->206us).

#define BM 128
#define BN 128
#define BK 32

// gfx9 s_waitcnt simm16: vmcnt[3:0]|expcnt[6:4]|lgkmcnt[11:8]|vmcnt_hi[15:14]
#define WAIT_VMCNT4 0x0F74   // vmcnt(4), lgkm/exp = no-wait
#define WAIT_VMCNT0 0x0F70   // vmcnt(0), lgkm/exp = no-wait

__device__ __forceinline__ void gl_lds16(const void* g, void* l) {
  __builtin_amdgcn_global_load_lds((const __attribute__((address_space(1))) void*)g,
                                   (__attribute__((address_space(3))) void*)l, 16, 0, 0);
}

template<bool BIAS_RELU>
__global__ __launch_bounds__(256, 4) void gemm_bt_kernel(
    const u16* __restrict__ A, const u16* __restrict__ Bt,
    u16* __restrict__ C, const float* __restrict__ bias,
    int M, int N, int K)
{
  __shared__ __align__(16) u16 As[2][BM * BK];
  __shared__ __align__(16) u16 Bs[2][BN * BK];
  int gm = (M + BM - 1) / BM;
  int gn = (N + BN - 1) / BN;
  int bid = blockIdx.x;
  int xcd = bid & 7;
  int t = bid >> 3;
  int trow = t / gn;
  int bn_i = t - trow * gn;
  int row = trow * 8 + xcd;
  if (row >= gm) return;
  int bm = row * BM, bn = bn_i * BN;

  int tid = threadIdx.x;
  int wave = tid >> 6, lane = tid & 63;
  int wm = wave & 1, wn = wave >> 1;

  // staging: 4 lanes per 32-elem row; logical quad permuted -> swizzled LDS layout
  int srow = tid >> 2;                                // 0..63
  int sq_log = ((tid & 3) - ((tid >> 3) & 3)) & 3;    // logical quad this lane stages
  int ar0 = min(bm + srow, M - 1);
  int ar1 = min(bm + 64 + srow, M - 1);
  int br0 = min(bn + srow, N - 1);
  int br1 = min(bn + 64 + srow, N - 1);
  const u16* ag0 = A + (size_t)ar0 * K + sq_log * 8;
  const u16* ag1 = A + (size_t)ar1 * K + sq_log * 8;
  const u16* bg0 = Bt + (size_t)br0 * K + sq_log * 8;
  const u16* bg1 = Bt + (size_t)br1 * K + sq_log * 8;
  int la0 = (wave * 16) * BK;
  int la1 = (64 + wave * 16) * BK;

  f32x4 acc[4][4];
  #pragma unroll
  for (int i = 0; i < 4; ++i)
    #pragma unroll
    for (int j = 0; j < 4; ++j)
      acc[i][j] = (f32x4){0.f, 0.f, 0.f, 0.f};

  int row16 = lane & 15, q = lane >> 4;
  int perm = (q + (row16 >> 1)) & 3;                  // physical quad for logical quad q
  int ard = (wm * 64 + row16) * BK + perm * 8;
  int brd = (wn * 64 + row16) * BK + perm * 8;

  const int iters = K / BK;

  // prologue: stage tile 0 into buffer 0
  gl_lds16(ag0, &As[0][la0]);
  gl_lds16(ag1, &As[0][la1]);
  gl_lds16(bg0, &Bs[0][la0]);
  gl_lds16(bg1, &Bs[0][la1]);

  int buf = 0;
  for (int it = 0; it < iters; ++it) {
    __builtin_amdgcn_s_barrier();
    if (it + 1 < iters) {
      int kn = (it + 1) * BK;
      gl_lds16(ag0 + kn, &As[buf ^ 1][la0]);
      gl_lds16(ag1 + kn, &As[buf ^ 1][la1]);
      gl_lds16(bg0 + kn, &Bs[buf ^ 1][la0]);
      gl_lds16(bg1 + kn, &Bs[buf ^ 1][la1]);
      __builtin_amdgcn_s_waitcnt(WAIT_VMCNT4);  // wait only current buf's 4 loads
    } else {
      __builtin_amdgcn_s_waitcnt(WAIT_VMCNT0);
    }
    __builtin_amdgcn_s_barrier();

    bf16x8 af[4], bfr[4];
    #pragma unroll
    for (int i = 0; i < 4; ++i) af[i] = *(const bf16x8*)(&As[buf][ard + i * 16 * BK]);
    #pragma unroll
    for (int j = 0; j < 4; ++j) bfr[j] = *(const bf16x8*)(&Bs[buf][brd + j * 16 * BK]);
    #pragma unroll
    for (int i = 0; i < 4; ++i)
      #pragma unroll
      for (int j = 0; j < 4; ++j)
        acc[i][j] = __builtin_amdgcn_mfma_f32_16x16x32_bf16(af[i], bfr[j], acc[i][j], 0, 0, 0);
    buf ^= 1;
  }

  // epilogue: C/D layout col=lane&15, row=(lane>>4)*4+reg  [verified m89/m91]
  #pragma unroll
  for (int i = 0; i < 4; ++i) {
    int rbase = bm + wm * 64 + i * 16 + q * 4;
    #pragma unroll
    for (int j = 0; j < 4; ++j) {
      int col = bn + wn * 64 + j * 16 + row16;
      if (col < N) {
        float bv = BIAS_RELU ? bias[col] : 0.f;
        #pragma unroll
        for (int r = 0; r < 4; ++r) {
          int gr = rbase + r;
          if (gr < M) {
            float val = acc[i][j][r];
            if (BIAS_RELU) { val += bv; val = fmaxf(val, 0.f); }
            C[(size_t)gr * N + col] = f2bf(val);
          }
        }
      }
    }
  }
}

static inline int gemm_grid(int M, int N) {
  int gm = (M + BM - 1) / BM;
  int gn = (N + BN - 1) / BN;
  int rows_per_xcd = (gm + 7) / 8;
  return rows_per_xcd * gn * 8;
}

// ---------------- launch ----------------

extern "C" void kernel_launch(void* const* d_in, const int* in_sizes, int n_in,
                              void* d_out, int out_size, void* d_ws, size_t ws_size,
                              hipStream_t stream) {
  const float* x   = (const float*)d_in[0];
  const int* ei    = (const int*)d_in[1];
  const int* src   = ei;
  const int* dst   = ei + NE;
  const float* W1  = (const float*)d_in[2];
  const float* b1  = (const float*)d_in[3];
  const float* W2  = (const float*)d_in[4];
  const float* b2  = (const float*)d_in[5];
  const float* W3  = (const float*)d_in[6];
  const float* b3  = (const float*)d_in[7];
  const float* W4  = (const float*)d_in[8];
  const float* b4  = (const float*)d_in[9];
  const float* W5  = (const float*)d_in[10];
  const float* b5  = (const float*)d_in[11];
  float* out_h = (float*)d_out;                       // 50000 x 192
  float* out_o = (float*)d_out + (size_t)NN * 192;    // 50000 x 5

  char* p = (char*)d_ws;
  auto alloc = [&](size_t bytes) { char* r = p; p += (bytes + 255) & ~(size_t)255; return r; };
  int*   deg      = (int*)alloc((size_t)NN * 4);
  int*   cursor   = (int*)alloc((size_t)NN * 4);
  float* dinv     = (float*)alloc((size_t)NN * 4);
  int*   offs     = (int*)alloc((size_t)(NN + 1) * 4);
  int2*  csr_pack = (int2*)alloc((size_t)NE * 8);
  u16* W1t = (u16*)alloc((size_t)768 * 1536 * 2);
  u16* W2t = (u16*)alloc((size_t)1536 * 768 * 2);
  u16* W3t = (u16*)alloc((size_t)768 * 384 * 2);
  u16* W4t = (u16*)alloc((size_t)384 * 192 * 2);
  u16* W5t = (u16*)alloc((size_t)192 * 5 * 2);
  u16* B0 = (u16*)alloc((size_t)NN * 768 * 2);
  u16* B1 = (u16*)alloc((size_t)NN * 768 * 2);
  u16* B2 = (u16*)alloc((size_t)NN * 1536 * 2);

  u16* xb  = B0;
  u16* a0  = B1;
  u16* h1  = B2;
  u16* g2  = B0;
  u16* h2  = B1;
  u16* g3  = B0;
  u16* h3  = B2;
  u16* g4  = B0;
  u16* h4b = B1;
  u16* g5  = B0;

  const int M = NN;

  // degree / CSR build
  zero_int_kernel<<<(NN + 255) / 256, 256, 0, stream>>>(deg, NN);
  zero_int_kernel<<<(NN + 255) / 256, 256, 0, stream>>>(cursor, NN);
  count_deg_kernel<<<(NE + 255) / 256, 256, 0, stream>>>(dst, deg, NE);
  dinv_kernel<<<(NN + 255) / 256, 256, 0, stream>>>(deg, dinv, NN);
  scan_kernel<<<1, 1024, 0, stream>>>(deg, offs, NN);
  csr_fill_kernel<<<(NE + 255) / 256, 256, 0, stream>>>(src, dst, offs, cursor, dinv,
                                                        csr_pack, NE);
  // dtype conversions
  f2bf_kernel<<<((NN * 768) + 255) / 256, 256, 0, stream>>>(x, xb, NN * 768);
  wt_kernel<<<((768 * 1536) + 255) / 256, 256, 0, stream>>>(W1, W1t, 768, 1536);
  wt_kernel<<<((1536 * 768) + 255) / 256, 256, 0, stream>>>(W2, W2t, 1536, 768);
  wt_kernel<<<((768 * 384) + 255) / 256, 256, 0, stream>>>(W3, W3t, 768, 384);
  wt_kernel<<<((384 * 192) + 255) / 256, 256, 0, stream>>>(W4, W4t, 384, 192);
  wt_kernel<<<((192 * 5) + 255) / 256, 256, 0, stream>>>(W5, W5t, 192, 5);

  dim3 blk(256);

  // layer 1: aggregate-first  (Ahat x) W1 + b1, relu
  agg8_kernel<96, false, false, true, false><<<(NN * 96 + 255) / 256, blk, 0, stream>>>(
      xb, offs, csr_pack, dinv, nullptr, a0, nullptr);
  gemm_bt_kernel<true><<<gemm_grid(M, 1536), blk, 0, stream>>>(
      a0, W1t, h1, b1, M, 1536, 768);

  // layer 2
  gemm_bt_kernel<false><<<gemm_grid(M, 768), blk, 0, stream>>>(
      h1, W2t, g2, nullptr, M, 768, 1536);
  agg8_kernel<96, true, true, true, false><<<(NN * 96 + 255) / 256, blk, 0, stream>>>(
      g2, offs, csr_pack, dinv, b2, h2, nullptr);

  // layer 3
  gemm_bt_kernel<false><<<gemm_grid(M, 384), blk, 0, stream>>>(
      h2, W3t, g3, nullptr, M, 384, 768);
  agg8_kernel<48, true, true, true, false><<<(NN * 48 + 255) / 256, blk, 0, stream>>>(
      g3, offs, csr_pack, dinv, b3, h3, nullptr);

  // layer 4 (output 0: fp32 h to d_out, bf16 copy for layer 5)
  gemm_bt_kernel<false><<<gemm_grid(M, 192), blk, 0, stream>>>(
      h3, W4t, g4, nullptr, M, 192, 384);
  agg8_kernel<24, true, true, true, true><<<(NN * 24 + 255) / 256, blk, 0, stream>>>(
      g4, offs, csr_pack, dinv, b4, h4b, out_h);

  // layer 5 (output 1)
  gemm_bt_kernel<false><<<gemm_grid(M, 5), blk, 0, stream>>>(
      h4b, W5t, g5, nullptr, M, 5, 192);
  agg_small_kernel<<<((NN * 5) + 255) / 256, 256, 0, stream>>>(
      g5, offs, csr_pack, dinv, b5, out_o, NN, 5);
}